// Round 4
// baseline (2442.646 us; speedup 1.0000x reference)
//
#include <hip/hip_runtime.h>
#include <cmath>

typedef unsigned int u32;

// Problem constants
#define NBATCH 128
#define NT 64
#define ND 768
#define NU 256
#define NV 48

// Residency split: rows 0..4*NR4-1 of Uw live in VGPRs, rest streamed from L2
#define NR4 22        // resident float4-rows per thread (88 of 256 rows)

// ws layout (bytes)
#define WS_INPW 0                          // inpW[128*64][1024] f32 = 33,554,432
#define WS_EMBW 33554432                   // embW[48][1024] f32   = 196,608
#define WS_UWS  (WS_EMBW + 196608)         // Uws [64][1024] float4 = 1,048,576
#define WS_WOT  (WS_UWS + 1048576)         // WotG[48][256] f32    = 49,152

__device__ __forceinline__ float sigf(float x) { return 1.0f / (1.0f + expf(-x)); }

// ---------------------------------------------------------------------------
// inpW[(b*64+t)][c] = inputs[b][t][:] @ W[256:1024][c]   (M=8192,N=1024,K=768)
// ---------------------------------------------------------------------------
__global__ __launch_bounds__(256) void prep_inpw(
    const float* __restrict__ inputs, const float* __restrict__ W,
    float* __restrict__ inpW) {
  __shared__ float Af[64][36];
  __shared__ float Bf[32][68];
  const int mt = blockIdx.x >> 4, nt = blockIdx.x & 15;
  const int m0 = mt * 64, n0 = nt * 64;
  const int tid = threadIdx.x;
  const int ty = tid >> 4, tx = tid & 15;
  const float4* in4 = (const float4*)inputs;
  const float4* W4 = (const float4*)W;
  float acc[4][4] = {};
  for (int kt = 0; kt < 24; ++kt) {
    __syncthreads();
    {
      int idx = tid;
#pragma unroll
      for (int r = 0; r < 2; ++r, idx += 256) {
        const int row = idx >> 3, k4 = idx & 7;
        const float4 a = in4[(size_t)(m0 + row) * 192 + kt * 8 + k4];
        *(float4*)&Af[row][4 * k4] = a;
      }
    }
    {
      int idx = tid;
#pragma unroll
      for (int r = 0; r < 2; ++r, idx += 256) {
        const int kk = idx >> 4, c4 = idx & 15;
        const float4 bv = W4[(size_t)(256 + kt * 32 + kk) * 256 + (n0 >> 2) + c4];
        *(float4*)&Bf[kk][4 * c4] = bv;
      }
    }
    __syncthreads();
#pragma unroll 4
    for (int kk = 0; kk < 32; ++kk) {
      float av[4], bv[4];
#pragma unroll
      for (int j = 0; j < 4; ++j) av[j] = Af[ty * 4 + j][kk];
#pragma unroll
      for (int j = 0; j < 4; ++j) bv[j] = Bf[kk][tx * 4 + j];
#pragma unroll
      for (int i = 0; i < 4; ++i)
#pragma unroll
        for (int j = 0; j < 4; ++j) acc[i][j] = fmaf(av[i], bv[j], acc[i][j]);
    }
  }
#pragma unroll
  for (int i = 0; i < 4; ++i) {
    const float4 o = make_float4(acc[i][0], acc[i][1], acc[i][2], acc[i][3]);
    ((float4*)inpW)[(((size_t)(m0 + ty * 4 + i)) * 1024 + n0 + tx * 4) >> 2] = o;
  }
}

// ---------------------------------------------------------------------------
// embW[v][c] = bias[c] + embed[v][:] @ W[0:256][c]
// ---------------------------------------------------------------------------
__global__ __launch_bounds__(256) void prep_embw(
    const float* __restrict__ embed, const float* __restrict__ W,
    const float* __restrict__ bias, float* __restrict__ embW) {
  const int v = blockIdx.x, tid = threadIdx.x;
  const float4* W4 = (const float4*)W;
  float4 acc = ((const float4*)bias)[tid];
  for (int e = 0; e < 256; ++e) {
    const float s = embed[v * 256 + e];
    const float4 w = W4[(size_t)e * 256 + tid];
    acc.x = fmaf(s, w.x, acc.x); acc.y = fmaf(s, w.y, acc.y);
    acc.z = fmaf(s, w.z, acc.z); acc.w = fmaf(s, w.w, acc.w);
  }
  ((float4*)embW)[v * 256 + tid] = acc;
}

// ---------------------------------------------------------------------------
// Uws element (k4, c) = float4{ Uw[4k4+0][c], .., Uw[4k4+3][c] }
// ---------------------------------------------------------------------------
__global__ __launch_bounds__(256) void prep_uws(
    const float* __restrict__ Uw, float* __restrict__ Uws) {
  const int k4 = blockIdx.x, tid = threadIdx.x;
#pragma unroll
  for (int j = 0; j < 4; ++j) {
    const int cc = tid + 256 * j;
    float4 o;
    o.x = Uw[(size_t)(4 * k4 + 0) * 1024 + cc];
    o.y = Uw[(size_t)(4 * k4 + 1) * 1024 + cc];
    o.z = Uw[(size_t)(4 * k4 + 2) * 1024 + cc];
    o.w = Uw[(size_t)(4 * k4 + 3) * 1024 + cc];
    ((float4*)Uws)[(size_t)k4 * 1024 + cc] = o;
  }
}

// Wot[v][u] = Wo[u][v]
__global__ void prep_wot(const float* __restrict__ Wo, float* __restrict__ WotG) {
  const int tid = threadIdx.x;
  for (int v = 0; v < NV; ++v) WotG[v * 256 + tid] = Wo[tid * NV + v];
}

// ---------------------------------------------------------------------------
// Persistent per-batch decoder: 64 blocks x 1024 threads, 2 batches/block,
// no cross-block communication. Thread c owns gate column c; Uw rows 0..87
// of column c live in VGPRs (loaded once), rows 88..255 streamed from L2.
// ---------------------------------------------------------------------------
__global__ __launch_bounds__(1024) void dec_main(
    const int* __restrict__ wids, const float* __restrict__ bo,
    const int* __restrict__ mlab, float* __restrict__ out,
    const float* __restrict__ inpW, const float* __restrict__ embW,
    const float* __restrict__ Uws, const float* __restrict__ WotG, int S) {

  const int tid = threadIdx.x;
  const int b0 = blockIdx.x * 2;

  __shared__ float hL[2][256];
  __shared__ float zL[2][1024];
  __shared__ float WotL[NV][260];
  __shared__ float lgp[2][NV][9];
  __shared__ float lg[2][NV];
  __shared__ int stL[4];              // tgt0, tgt1, adj0, adj1
  __shared__ int tsL[2];

  // ---- init ----
  if (tid < 512) hL[tid >> 8][tid & 255] = 0.f;
  if (tid == 0) { stL[0] = 1; stL[1] = 1; stL[2] = 0; stL[3] = 0; tsL[0] = 0; tsL[1] = 0; }
  for (int i = tid; i < NV * 256; i += 1024) WotL[i >> 8][i & 255] = WotG[i];
  __syncthreads();
  if (tid < 128) {
    const int b = tid >> 6, t = tid & 63;
    if (wids[(b0 + b) * NT + t] != 0) atomicAdd(&tsL[b], 1);
  }
  float cst = 0.f;   // c-state for threads tid<512: (b=tid>>8, u=tid&255)

  const float4* Uws4 = (const float4*)Uws;
  const int c = tid;

  // ---- resident weight slice: rows 0..4*NR4-1 of column c ----
  float4 UR[NR4];
#pragma unroll
  for (int j = 0; j < NR4; ++j) UR[j] = Uws4[(size_t)j * 1024 + c];

  __syncthreads();

  int tsb = 0, ml = 3, hai = 0, hreps = 0;
  if (tid < 2) { tsb = tsL[tid]; ml = mlab[0]; }

#define DOT4(ACC, WV, HV)                                                      \
  ACC = fmaf((WV).x, (HV).x, fmaf((WV).y, (HV).y,                              \
        fmaf((WV).z, (HV).z, fmaf((WV).w, (HV).w, (ACC)))));

  for (int s = 0; s < S; ++s) {
    // table terms for x@W (issued early, hidden under the k-loop)
    const int t0 = stL[0], t1 = stL[1], a0 = stL[2], a1 = stL[3];
    const float e0 = embW[t0 * 1024 + c];
    const float e1 = embW[t1 * 1024 + c];
    const float q0 = inpW[(size_t)((b0) * 64 + a0) * 1024 + c];
    const float q1 = inpW[(size_t)((b0 + 1) * 64 + a1) * 1024 + c];

    // ---- streamed part: rows 4*NR4..255 (prefetch-friendly simple loop) ----
    float s0a = 0.f, s0b = 0.f, s1a = 0.f, s1b = 0.f;
#pragma unroll 6
    for (int k4 = NR4; k4 < 64; ++k4) {
      const float4 wv = Uws4[(size_t)k4 * 1024 + c];
      const float4 h0 = *(const float4*)&hL[0][4 * k4];
      const float4 h1 = *(const float4*)&hL[1][4 * k4];
      if (k4 & 1) { DOT4(s0b, wv, h0) DOT4(s1b, wv, h1) }
      else        { DOT4(s0a, wv, h0) DOT4(s1a, wv, h1) }
    }

    // ---- resident part: rows 0..4*NR4-1, weights already in VGPRs ----
    float r0a = 0.f, r0b = 0.f, r1a = 0.f, r1b = 0.f;
#pragma unroll
    for (int j = 0; j < NR4; ++j) {
      const float4 h0 = *(const float4*)&hL[0][4 * j];
      const float4 h1 = *(const float4*)&hL[1][4 * j];
      if (j & 1) { DOT4(r0b, UR[j], h0) DOT4(r1b, UR[j], h1) }
      else       { DOT4(r0a, UR[j], h0) DOT4(r1a, UR[j], h1) }
    }

    zL[0][c] = ((r0a + r0b) + (s0a + s0b)) + e0 + q0;
    zL[1][c] = ((r1a + r1b) + (s1a + s1b)) + e1 + q1;
    __syncthreads();

    // ---- LSTM pointwise (keras gate order i,f,g,o) ----
    if (tid < 512) {
      const int b = tid >> 8, u = tid & 255;
      const float zi = zL[b][u], zf = zL[b][256 + u];
      const float zg = zL[b][512 + u], zo = zL[b][768 + u];
      const float cn = sigf(zf) * cst + sigf(zi) * tanhf(zg);
      cst = cn;
      hL[b][u] = sigf(zo) * tanhf(cn);
    }
    __syncthreads();

    // ---- logits partials: (b, v, kp) each 32 k (k = kp + 8i) ----
    {
      const int b = tid >> 9, idx = tid & 511, v = idx >> 3, kp = idx & 7;
      if (v < NV) {
        float sm = 0.f;
#pragma unroll 8
        for (int i = 0; i < 32; ++i) {
          const int k = kp + 8 * i;
          sm = fmaf(hL[b][k], WotL[v][k], sm);
        }
        lgp[b][v][kp] = sm;
      }
    }
    __syncthreads();
    if (tid < 128) {
      const int b = tid >> 6, v = tid & 63;
      if (v < NV) {
        float sm = bo[v];
#pragma unroll
        for (int k = 0; k < 8; ++k) sm += lgp[b][v][k];
        lg[b][v] = sm;
      }
    }
    __syncthreads();

    // ---- argmax (first-max tie-break) + bookkeeping ----
    if (tid < 2) {
      const int b = tid;
      int am = 0;
      float bv = lg[b][0];
      for (int v = 1; v < NV; ++v) {
        const float x = lg[b][v];
        if (x > bv) { bv = x; am = v; }
      }
      const int preds = (hreps >= ml) ? 2 : am;
      const int res = (hai == tsb) ? 0 : preds;
      out[(size_t)(b0 + b) * S + s] = (float)res;
      const int inc = (preds == 2 && hai < tsb) ? 1 : 0;
      hai += inc;
      hreps = inc ? 0 : hreps;
      stL[b] = preds;
      stL[2 + b] = (hai < tsb) ? hai : hai - 1;
    }
    __syncthreads();
  }
#undef DOT4
}

// ---------------------------------------------------------------------------
extern "C" void kernel_launch(void* const* d_in, const int* in_sizes, int n_in,
                              void* d_out, int out_size, void* d_ws, size_t ws_size,
                              hipStream_t stream) {
  const float* inputs = (const float*)d_in[0];
  const int*   wids   = (const int*)d_in[1];
  const float* embed  = (const float*)d_in[2];
  const float* W      = (const float*)d_in[3];
  const float* Uw     = (const float*)d_in[4];
  const float* bias   = (const float*)d_in[5];
  const float* Wo     = (const float*)d_in[6];
  const float* bo     = (const float*)d_in[7];
  const int*   mlab   = (const int*)d_in[8];
  float* out = (float*)d_out;
  const int S = out_size / NBATCH;   // 192

  char* ws = (char*)d_ws;
  float* inpW = (float*)(ws + WS_INPW);
  float* embW = (float*)(ws + WS_EMBW);
  float* Uws  = (float*)(ws + WS_UWS);
  float* WotG = (float*)(ws + WS_WOT);

  prep_inpw<<<2048, 256, 0, stream>>>(inputs, W, inpW);
  prep_embw<<<48, 256, 0, stream>>>(embed, W, bias, embW);
  prep_uws<<<64, 256, 0, stream>>>(Uw, Uws);
  prep_wot<<<1, 256, 0, stream>>>(Wo, WotG);
  dec_main<<<64, 1024, 0, stream>>>(wids, bo, mlab, out, inpW, embW, Uws, WotG, S);
}